// Round 14
// baseline (260.113 us; speedup 1.0000x reference)
//
#include <hip/hip_runtime.h>
#include <math.h>

// ---------------------------------------------------------------------------
// InfoNCE on MI355X — v17.
// T1[i,j] = tail(relu(hx[j]+hy[i]+b1)) = fused GEMM M=262144, N=512, K=512,
// A formed on the fly; ONE MFMA product (A bf16 x W2 bf16), 32x32x16.
// v17 vs v16: 3-DEEP B PREFETCH AT ZERO REGISTER COST. v16 accounting:
// P ~= 1630 cyc/half-step vs resource floors (MFMA 512/SIMD, L2 ~585, LDS
// 384) -> latency x concurrency deficit: 2-deep prefetch keeps only 2KB
// in flight per wave (32KB/CU); at ~1000cyc loaded L2 latency Little's law
// caps delivery at ~30 B/cyc ~= measured P. The Bh ring ALREADY has 4
// buffers (32 regs): issue hs+3 at hs (slot (hs+3)&3 freed at hs-1) ->
// 6 loads in flight per wave, 96KB/CU, delivery ceiling-bound not
// latency-bound. Single change; v16 verbatim otherwise (counter-verified:
// WRITE 258KB no-spill, FETCH 6.8MB, fence-free epilogue, absmax = 1 bf16
// ulp of the output scalar since v4).
// ---------------------------------------------------------------------------

typedef __bf16 bf16x8 __attribute__((ext_vector_type(8)));
typedef float  f32x16 __attribute__((ext_vector_type(16)));

#define H     512
#define NPTS  512
#define XD    128
#define SPA   520   // A-tile LDS row stride (elems): 1040 B (0 conflicts)
#define PLS   12    // epilogue partial-scratch row stride (f32)
#define NTILE 4096  // 64 i-groups x 64 j-groups (M-tile 64 = 8i x 8j)

// ---------------- prep: hx, hy(+b1); W2 -> bf16 fragment-major; zero ------
__global__ __launch_bounds__(256) void prep_kernel(
    const float* __restrict__ x, const float* __restrict__ y,
    const float* __restrict__ W1x, const float* __restrict__ W1y,
    const float* __restrict__ b1, const float* __restrict__ W2,
    float* __restrict__ hx, float* __restrict__ hy,
    __bf16* __restrict__ w2h,
    float* __restrict__ rsm, int* __restrict__ ctl) {
  __shared__ float xs[8 * XD];
  const int b = blockIdx.x;
  const int t = threadIdx.x;
  if (b < 128) {
    const bool isY = (b >= 64);
    const int r0 = (isY ? b - 64 : b) * 8;
    const float* src = isY ? y : x;      // [NPTS][XD]
    const float* W   = isY ? W1y : W1x;  // [XD][H]
    float* dst = isY ? hy : hx;
    for (int i = t; i < 8 * XD; i += 256) xs[i] = src[r0 * XD + i];
    __syncthreads();
    float a0[8], a1[8];
#pragma unroll
    for (int r = 0; r < 8; ++r) { a0[r] = 0.f; a1[r] = 0.f; }
    for (int k = 0; k < XD; ++k) {       // W1 row k read once, used 8x
      const float w0 = W[k * H + t];
      const float w1 = W[k * H + t + 256];
#pragma unroll
      for (int r = 0; r < 8; ++r) {
        const float xv = xs[r * XD + k];   // LDS broadcast
        a0[r] = fmaf(xv, w0, a0[r]);
        a1[r] = fmaf(xv, w1, a1[r]);
      }
    }
    const float c0 = isY ? b1[t] : 0.f;        // fold b1 into hy
    const float c1 = isY ? b1[t + 256] : 0.f;
#pragma unroll
    for (int r = 0; r < 8; ++r) {
      dst[(r0 + r) * H + t]       = a0[r] + c0;
      dst[(r0 + r) * H + t + 256] = a1[r] + c1;
    }
  } else {
    // W2[k][n] -> 32x32x16-fragment-major bf16 (hi only):
    // idx = ((n>>5)*32 + (k>>4))*512 + (n&31)*16 + (k&15)
    const int n = b - 128;
    if (n == 0) { rsm[t] = 0.f; rsm[t + 256] = 0.f; if (t == 0) ctl[0] = 0; }
    for (int k = t; k < H; k += 256) {
      const int idx = (((n >> 5) * 32) + (k >> 4)) * 512 + (n & 31) * 16 + (k & 15);
      w2h[idx] = (__bf16)W2[k * H + n];
    }
  }
}

// ---------------- pair GEMM + fused tail + row sums + final ---------------
// grid 4096; M-tile 64 (8i x 8j); 512 thr / 8 waves; wave tile 64x64
// (acc[2][2] f32x16). K in 32 half-steps of 16; ONE product per (mt,nt);
// B 3-deep prefetched in the 4-buffer ring Bh[4][2] (unroll 4, walking
// pointer), A 1-deep from LDS. Barrier-free. Fence-free atomic epilogue.
__global__ __launch_bounds__(512, 4) void pair_kernel(
    const float* __restrict__ hx, const float* __restrict__ hy,
    const __bf16* __restrict__ w2h,
    const float* __restrict__ b2, const float* __restrict__ W3,
    const float* __restrict__ b3, float* __restrict__ t0g,
    float* __restrict__ rsm, int* __restrict__ ctl,
    float* __restrict__ out) {
  extern __shared__ __align__(16) __bf16 Ah[];   // [64][SPA] = 66560 B
  __shared__ float s1[8], s2[8];
  __shared__ int rank_s;

  const int t    = threadIdx.x;
  const int i0   = (blockIdx.x >> 6) * 8;
  const int j0   = (blockIdx.x & 63) * 8;
  const int wave = t >> 6;        // n-group 0..7 (cols wave*64..wave*64+63)
  const int lane = t & 63;
  const int r31  = lane & 31;
  const int half = lane >> 5;

  const int boff = r31 * 16 + half * 8;
  const __bf16* w2hW = w2h + wave * 32768 + boff;

  // issue B loads for half-steps 0,1,2 before staging (land during it)
  bf16x8 Bh[4][2];
  Bh[0][0] = *(const bf16x8*)(w2hW);
  Bh[0][1] = *(const bf16x8*)(w2hW + 16384);
  Bh[1][0] = *(const bf16x8*)(w2hW + 512);
  Bh[1][1] = *(const bf16x8*)(w2hW + 16384 + 512);
  Bh[2][0] = *(const bf16x8*)(w2hW + 1024);
  Bh[2][1] = *(const bf16x8*)(w2hW + 16384 + 1024);

  // ---- upfront staging of the whole 64 x 512 A tile ------------------
  {
    const int sm = t >> 3;        // pair row 0..63  (ti = sm>>3, tj = sm&7)
    const int sl = t & 7;
    const float* hxp = hx + (j0 + (sm & 7)) * H;
    const float* hyp = hy + (i0 + (sm >> 3)) * H;
    __bf16* arow = Ah + sm * SPA;
#pragma unroll
    for (int c = 0; c < 8; ++c) {
      const int k = sl * 8 + c * 64;
      float4 x0 = *(const float4*)(hxp + k);
      float4 x1 = *(const float4*)(hxp + k + 4);
      float4 y0 = *(const float4*)(hyp + k);
      float4 y1 = *(const float4*)(hyp + k + 4);
      float a[8] = {x0.x + y0.x, x0.y + y0.y, x0.z + y0.z, x0.w + y0.w,
                    x1.x + y1.x, x1.y + y1.y, x1.z + y1.z, x1.w + y1.w};
      bf16x8 hv;
#pragma unroll
      for (int e = 0; e < 8; ++e) {
        float v = a[e] > 0.f ? a[e] : 0.f;   // first relu
        hv[e] = (__bf16)v;
      }
      *(bf16x8*)(&arow[k]) = hv;
    }
  }

  f32x16 acc[2][2] = {};
  __syncthreads();   // staging complete; only barrier before epilogue

  // walking pointers (the ONLY per-iter address state: +512 / +16 elems)
  const __bf16* pBh = w2hW;     // points at frag of half-step hs
  const __bf16* pA  = Ah + r31 * SPA + half * 8;

  bf16x8 Ab[2][2];
  Ab[0][0] = *(const bf16x8*)(pA);
  Ab[0][1] = *(const bf16x8*)(pA + 32 * SPA);

  // ---- barrier-free K-loop: 32 half-steps, B prefetched 3 deep -------
#pragma unroll 4
  for (int hs = 0; hs < 32; ++hs) {
    const int cur = hs & 3;
    const int ca  = hs & 1;
    if (hs < 29) {   // prefetch B for half-step hs+3 (slot freed at hs-1)
      Bh[(hs + 3) & 3][0] = *(const bf16x8*)(pBh + 1536);
      Bh[(hs + 3) & 3][1] = *(const bf16x8*)(pBh + 16384 + 1536);
    }
    if (hs < 31) {   // prefetch A for half-step hs+1 (LDS, short latency)
      Ab[ca ^ 1][0] = *(const bf16x8*)(pA + 16);
      Ab[ca ^ 1][1] = *(const bf16x8*)(pA + 32 * SPA + 16);
    }
    pBh += 512; pA += 16;
    __builtin_amdgcn_s_setprio(1);
    acc[0][0] = __builtin_amdgcn_mfma_f32_32x32x16_bf16(Ab[ca][0], Bh[cur][0], acc[0][0], 0, 0, 0);
    acc[0][1] = __builtin_amdgcn_mfma_f32_32x32x16_bf16(Ab[ca][0], Bh[cur][1], acc[0][1], 0, 0, 0);
    acc[1][0] = __builtin_amdgcn_mfma_f32_32x32x16_bf16(Ab[ca][1], Bh[cur][0], acc[1][0], 0, 0, 0);
    acc[1][1] = __builtin_amdgcn_mfma_f32_32x32x16_bf16(Ab[ca][1], Bh[cur][1], acc[1][1], 0, 0, 0);
    __builtin_amdgcn_s_setprio(0);
  }

  __syncthreads();   // all waves done reading Ah -> safe to alias its LDS

  // ---- epilogue: relu(h2+b2)*W3, shfl-reduce, softplus, row sums -----
  float* PL = (float*)Ah;            // [64][PLS], aliases dead A tile
  const float bb0 = b2[wave * 64 + r31];
  const float bb1 = b2[wave * 64 + 32 + r31];
  const float w30 = W3[wave * 64 + r31];
  const float w31 = W3[wave * 64 + 32 + r31];
#pragma unroll
  for (int mt = 0; mt < 2; ++mt) {
#pragma unroll
    for (int r = 0; r < 16; ++r) {
      float v0 = acc[mt][0][r] + bb0;
      float v1 = acc[mt][1][r] + bb1;
      v0 = v0 > 0.f ? v0 : 0.f;            // second relu
      v1 = v1 > 0.f ? v1 : 0.f;
      float p = fmaf(v0, w30, v1 * w31);
      p += __shfl_xor(p, 1);
      p += __shfl_xor(p, 2);
      p += __shfl_xor(p, 4);
      p += __shfl_xor(p, 8);
      p += __shfl_xor(p, 16);
      if (r31 == 0) {
        const int row = mt * 32 + (r & 3) + 8 * (r >> 2) + 4 * half;
        PL[row * PLS + wave] = p;
      }
    }
  }
  __syncthreads();
  if (t < 64) {
    float4 q0 = *(const float4*)(PL + t * PLS);
    float4 q1 = *(const float4*)(PL + t * PLS + 4);
    float s = b3[0] + q0.x + q0.y + q0.z + q0.w + q1.x + q1.y + q1.z + q1.w;
    const float sp = s > 0.f ? s + log1pf(expf(-s)) : log1pf(expf(s));
    const int ti = t >> 3, tj = t & 7;
    const int gi = i0 + ti, gj = j0 + tj;
    if (gi == gj)                           // diag == T0, coherent store
      __hip_atomic_store(t0g + gi, sp, __ATOMIC_RELAXED,
                         __HIP_MEMORY_SCOPE_AGENT);
    float e = expf(sp);
    e += __shfl_xor(e, 1);                 // sum over this tile's 8 j's
    e += __shfl_xor(e, 2);
    e += __shfl_xor(e, 4);
    if (tj == 0) atomicAdd(rsm + gi, e);
  }
  __syncthreads();   // vmcnt(0) drain: data atomics complete before rank

  // ---- last block does the final reduction (NO fences) ---------------
  if (t == 0) rank_s = atomicAdd(ctl, 1);
  __syncthreads();
  if (rank_s == NTILE - 1) {
    float a = __hip_atomic_load(t0g + t, __ATOMIC_RELAXED,
                                __HIP_MEMORY_SCOPE_AGENT);
    float l = logf(__hip_atomic_load(rsm + t, __ATOMIC_RELAXED,
                                     __HIP_MEMORY_SCOPE_AGENT));
#pragma unroll
    for (int off = 1; off < 64; off <<= 1) {
      a += __shfl_xor(a, off);
      l += __shfl_xor(l, off);
    }
    if (lane == 0) { s1[wave] = a; s2[wave] = l; }
    __syncthreads();
    if (t == 0) {
      float sa = 0.f, sb = 0.f;
#pragma unroll
      for (int i = 0; i < 8; ++i) { sa += s1[i]; sb += s2[i]; }
      out[0] = sa / 512.0f - sb / 512.0f + logf(512.0f);
    }
  }
}

// ---------------------------------------------------------------------------
extern "C" void kernel_launch(void* const* d_in, const int* in_sizes, int n_in,
                              void* d_out, int out_size, void* d_ws, size_t ws_size,
                              hipStream_t stream) {
  const float* x   = (const float*)d_in[0];
  const float* y   = (const float*)d_in[1];
  const float* W1x = (const float*)d_in[2];
  const float* W1y = (const float*)d_in[3];
  const float* b1  = (const float*)d_in[4];
  const float* W2  = (const float*)d_in[5];
  const float* b2  = (const float*)d_in[6];
  const float* W3  = (const float*)d_in[7];
  const float* b3  = (const float*)d_in[8];

  float* ws = (float*)d_ws;
  float* hx  = ws;                        // 512*512 f32
  float* hy  = ws + 262144;               // 512*512 f32
  float* t0g = ws + 524288;               // 512 f32 (diag = T0)
  float* rsm = ws + 524288 + 512;         // 512 f32 (row exp-sums)
  int*   ctl = (int*)(ws + 524288 + 1024);// rank counter
  __bf16* w2h = (__bf16*)(ws + 786432);   // 512*512 bf16 (fragment-major)
  float* out = (float*)d_out;

  static bool configured = false;
  if (!configured) {
    hipFuncSetAttribute(reinterpret_cast<const void*>(pair_kernel),
                        hipFuncAttributeMaxDynamicSharedMemorySize,
                        64 * SPA * 2);
    configured = true;
  }

  hipLaunchKernelGGL(prep_kernel, dim3(640), dim3(256), 0, stream,
                     x, y, W1x, W1y, b1, W2, hx, hy, w2h, rsm, ctl);
  hipLaunchKernelGGL(pair_kernel, dim3(NTILE), dim3(512), 64 * SPA * 2, stream,
                     hx, hy, w2h, b2, W3, b3, t0g, rsm, ctl, out);
}

// Round 15
// 256.227 us; speedup vs baseline: 1.0152x; 1.0152x over previous
//
#include <hip/hip_runtime.h>
#include <math.h>

// ---------------------------------------------------------------------------
// InfoNCE on MI355X — v18.
// T1[i,j] = tail(relu(hx[j]+hy[i]+b1)) = fused GEMM M=262144, N=512, K=512,
// A formed on the fly; ONE MFMA product (A bf16 x W2 bf16), 32x32x16.
// v18 vs v16/v17: SETPRIO ABLATION. v17's 3-deep prefetch was null->negative
// (198->203-208us): loads already land ~3000cyc early at 2-deep; depth was
// never the limiter. Remaining un-ablated lever: s_setprio around the MFMA
// cluster — platform A/B evidence (m190) shows setprio HURTS non-phase-split
// GEMM loops (no wave role-split -> nothing to arbitrate; prio-1 clusters
// deprioritize co-resident waves' load issue, serializing cluster-then-load).
// Cargo-culted since v4, never ablated. v18 = v16 exact body (2-deep B ring,
// the faster of v16/v17), setprio deleted, A ds_reads issued before B
// globals (short-latency op first). Everything else counter-verified
// unchanged (WRITE 258KB no-spill, FETCH 6.8MB, fence-free epilogue,
// absmax = 1 bf16 ulp of the output scalar). Pre-commitment: if null,
// declare structural ceiling (B-L2 floor 585 cyc/hs ~ MFMA 512 ~ wall 928).
// ---------------------------------------------------------------------------

typedef __bf16 bf16x8 __attribute__((ext_vector_type(8)));
typedef float  f32x16 __attribute__((ext_vector_type(16)));

#define H     512
#define NPTS  512
#define XD    128
#define SPA   520   // A-tile LDS row stride (elems): 1040 B (0 conflicts)
#define PLS   12    // epilogue partial-scratch row stride (f32)
#define NTILE 4096  // 64 i-groups x 64 j-groups (M-tile 64 = 8i x 8j)

// ---------------- prep: hx, hy(+b1); W2 -> bf16 fragment-major; zero ------
__global__ __launch_bounds__(256) void prep_kernel(
    const float* __restrict__ x, const float* __restrict__ y,
    const float* __restrict__ W1x, const float* __restrict__ W1y,
    const float* __restrict__ b1, const float* __restrict__ W2,
    float* __restrict__ hx, float* __restrict__ hy,
    __bf16* __restrict__ w2h,
    float* __restrict__ rsm, int* __restrict__ ctl) {
  __shared__ float xs[8 * XD];
  const int b = blockIdx.x;
  const int t = threadIdx.x;
  if (b < 128) {
    const bool isY = (b >= 64);
    const int r0 = (isY ? b - 64 : b) * 8;
    const float* src = isY ? y : x;      // [NPTS][XD]
    const float* W   = isY ? W1y : W1x;  // [XD][H]
    float* dst = isY ? hy : hx;
    for (int i = t; i < 8 * XD; i += 256) xs[i] = src[r0 * XD + i];
    __syncthreads();
    float a0[8], a1[8];
#pragma unroll
    for (int r = 0; r < 8; ++r) { a0[r] = 0.f; a1[r] = 0.f; }
    for (int k = 0; k < XD; ++k) {       // W1 row k read once, used 8x
      const float w0 = W[k * H + t];
      const float w1 = W[k * H + t + 256];
#pragma unroll
      for (int r = 0; r < 8; ++r) {
        const float xv = xs[r * XD + k];   // LDS broadcast
        a0[r] = fmaf(xv, w0, a0[r]);
        a1[r] = fmaf(xv, w1, a1[r]);
      }
    }
    const float c0 = isY ? b1[t] : 0.f;        // fold b1 into hy
    const float c1 = isY ? b1[t + 256] : 0.f;
#pragma unroll
    for (int r = 0; r < 8; ++r) {
      dst[(r0 + r) * H + t]       = a0[r] + c0;
      dst[(r0 + r) * H + t + 256] = a1[r] + c1;
    }
  } else {
    // W2[k][n] -> 32x32x16-fragment-major bf16 (hi only):
    // idx = ((n>>5)*32 + (k>>4))*512 + (n&31)*16 + (k&15)
    const int n = b - 128;
    if (n == 0) { rsm[t] = 0.f; rsm[t + 256] = 0.f; if (t == 0) ctl[0] = 0; }
    for (int k = t; k < H; k += 256) {
      const int idx = (((n >> 5) * 32) + (k >> 4)) * 512 + (n & 31) * 16 + (k & 15);
      w2h[idx] = (__bf16)W2[k * H + n];
    }
  }
}

// ---------------- pair GEMM + fused tail + row sums + final ---------------
// grid 4096; M-tile 64 (8i x 8j); 512 thr / 8 waves; wave tile 64x64
// (acc[2][2] f32x16). K in 32 half-steps of 16; ONE product per (mt,nt);
// B 2-deep in Bh[4][2] ring (unroll 4, walking pointers), A 1-deep from
// LDS (ds_reads issued first). Barrier-free. NO setprio. Fence-free
// atomic epilogue + last-block final reduction.
__global__ __launch_bounds__(512, 4) void pair_kernel(
    const float* __restrict__ hx, const float* __restrict__ hy,
    const __bf16* __restrict__ w2h,
    const float* __restrict__ b2, const float* __restrict__ W3,
    const float* __restrict__ b3, float* __restrict__ t0g,
    float* __restrict__ rsm, int* __restrict__ ctl,
    float* __restrict__ out) {
  extern __shared__ __align__(16) __bf16 Ah[];   // [64][SPA] = 66560 B
  __shared__ float s1[8], s2[8];
  __shared__ int rank_s;

  const int t    = threadIdx.x;
  const int i0   = (blockIdx.x >> 6) * 8;
  const int j0   = (blockIdx.x & 63) * 8;
  const int wave = t >> 6;        // n-group 0..7 (cols wave*64..wave*64+63)
  const int lane = t & 63;
  const int r31  = lane & 31;
  const int half = lane >> 5;

  const int boff = r31 * 16 + half * 8;
  const __bf16* w2hW = w2h + wave * 32768 + boff;

  // issue B loads for half-steps 0 and 1 before staging (land during it)
  bf16x8 Bh[4][2];
  Bh[0][0] = *(const bf16x8*)(w2hW);
  Bh[0][1] = *(const bf16x8*)(w2hW + 16384);
  Bh[1][0] = *(const bf16x8*)(w2hW + 512);
  Bh[1][1] = *(const bf16x8*)(w2hW + 16384 + 512);

  // ---- upfront staging of the whole 64 x 512 A tile ------------------
  {
    const int sm = t >> 3;        // pair row 0..63  (ti = sm>>3, tj = sm&7)
    const int sl = t & 7;
    const float* hxp = hx + (j0 + (sm & 7)) * H;
    const float* hyp = hy + (i0 + (sm >> 3)) * H;
    __bf16* arow = Ah + sm * SPA;
#pragma unroll
    for (int c = 0; c < 8; ++c) {
      const int k = sl * 8 + c * 64;
      float4 x0 = *(const float4*)(hxp + k);
      float4 x1 = *(const float4*)(hxp + k + 4);
      float4 y0 = *(const float4*)(hyp + k);
      float4 y1 = *(const float4*)(hyp + k + 4);
      float a[8] = {x0.x + y0.x, x0.y + y0.y, x0.z + y0.z, x0.w + y0.w,
                    x1.x + y1.x, x1.y + y1.y, x1.z + y1.z, x1.w + y1.w};
      bf16x8 hv;
#pragma unroll
      for (int e = 0; e < 8; ++e) {
        float v = a[e] > 0.f ? a[e] : 0.f;   // first relu
        hv[e] = (__bf16)v;
      }
      *(bf16x8*)(&arow[k]) = hv;
    }
  }

  f32x16 acc[2][2] = {};
  __syncthreads();   // staging complete; only barrier before epilogue

  // walking pointers (the ONLY per-iter address state: +512 / +16 elems)
  const __bf16* pBh = w2hW;     // points at frag of half-step hs
  const __bf16* pA  = Ah + r31 * SPA + half * 8;

  bf16x8 Ab[2][2];
  Ab[0][0] = *(const bf16x8*)(pA);
  Ab[0][1] = *(const bf16x8*)(pA + 32 * SPA);

  // ---- barrier-free K-loop: 32 half-steps, B 2-deep, no setprio ------
#pragma unroll 4
  for (int hs = 0; hs < 32; ++hs) {
    const int cur = hs & 3;
    const int ca  = hs & 1;
    if (hs < 31) {   // A prefetch first (LDS, short latency, lgkm counter)
      Ab[ca ^ 1][0] = *(const bf16x8*)(pA + 16);
      Ab[ca ^ 1][1] = *(const bf16x8*)(pA + 32 * SPA + 16);
    }
    if (hs < 30) {   // B prefetch for half-step hs+2 (vm counter)
      Bh[(hs + 2) & 3][0] = *(const bf16x8*)(pBh + 1024);
      Bh[(hs + 2) & 3][1] = *(const bf16x8*)(pBh + 16384 + 1024);
    }
    pBh += 512; pA += 16;
    acc[0][0] = __builtin_amdgcn_mfma_f32_32x32x16_bf16(Ab[ca][0], Bh[cur][0], acc[0][0], 0, 0, 0);
    acc[0][1] = __builtin_amdgcn_mfma_f32_32x32x16_bf16(Ab[ca][0], Bh[cur][1], acc[0][1], 0, 0, 0);
    acc[1][0] = __builtin_amdgcn_mfma_f32_32x32x16_bf16(Ab[ca][1], Bh[cur][0], acc[1][0], 0, 0, 0);
    acc[1][1] = __builtin_amdgcn_mfma_f32_32x32x16_bf16(Ab[ca][1], Bh[cur][1], acc[1][1], 0, 0, 0);
  }

  __syncthreads();   // all waves done reading Ah -> safe to alias its LDS

  // ---- epilogue: relu(h2+b2)*W3, shfl-reduce, softplus, row sums -----
  float* PL = (float*)Ah;            // [64][PLS], aliases dead A tile
  const float bb0 = b2[wave * 64 + r31];
  const float bb1 = b2[wave * 64 + 32 + r31];
  const float w30 = W3[wave * 64 + r31];
  const float w31 = W3[wave * 64 + 32 + r31];
#pragma unroll
  for (int mt = 0; mt < 2; ++mt) {
#pragma unroll
    for (int r = 0; r < 16; ++r) {
      float v0 = acc[mt][0][r] + bb0;
      float v1 = acc[mt][1][r] + bb1;
      v0 = v0 > 0.f ? v0 : 0.f;            // second relu
      v1 = v1 > 0.f ? v1 : 0.f;
      float p = fmaf(v0, w30, v1 * w31);
      p += __shfl_xor(p, 1);
      p += __shfl_xor(p, 2);
      p += __shfl_xor(p, 4);
      p += __shfl_xor(p, 8);
      p += __shfl_xor(p, 16);
      if (r31 == 0) {
        const int row = mt * 32 + (r & 3) + 8 * (r >> 2) + 4 * half;
        PL[row * PLS + wave] = p;
      }
    }
  }
  __syncthreads();
  if (t < 64) {
    float4 q0 = *(const float4*)(PL + t * PLS);
    float4 q1 = *(const float4*)(PL + t * PLS + 4);
    float s = b3[0] + q0.x + q0.y + q0.z + q0.w + q1.x + q1.y + q1.z + q1.w;
    const float sp = s > 0.f ? s + log1pf(expf(-s)) : log1pf(expf(s));
    const int ti = t >> 3, tj = t & 7;
    const int gi = i0 + ti, gj = j0 + tj;
    if (gi == gj)                           // diag == T0, coherent store
      __hip_atomic_store(t0g + gi, sp, __ATOMIC_RELAXED,
                         __HIP_MEMORY_SCOPE_AGENT);
    float e = expf(sp);
    e += __shfl_xor(e, 1);                 // sum over this tile's 8 j's
    e += __shfl_xor(e, 2);
    e += __shfl_xor(e, 4);
    if (tj == 0) atomicAdd(rsm + gi, e);
  }
  __syncthreads();   // vmcnt(0) drain: data atomics complete before rank

  // ---- last block does the final reduction (NO fences) ---------------
  if (t == 0) rank_s = atomicAdd(ctl, 1);
  __syncthreads();
  if (rank_s == NTILE - 1) {
    float a = __hip_atomic_load(t0g + t, __ATOMIC_RELAXED,
                                __HIP_MEMORY_SCOPE_AGENT);
    float l = logf(__hip_atomic_load(rsm + t, __ATOMIC_RELAXED,
                                     __HIP_MEMORY_SCOPE_AGENT));
#pragma unroll
    for (int off = 1; off < 64; off <<= 1) {
      a += __shfl_xor(a, off);
      l += __shfl_xor(l, off);
    }
    if (lane == 0) { s1[wave] = a; s2[wave] = l; }
    __syncthreads();
    if (t == 0) {
      float sa = 0.f, sb = 0.f;
#pragma unroll
      for (int i = 0; i < 8; ++i) { sa += s1[i]; sb += s2[i]; }
      out[0] = sa / 512.0f - sb / 512.0f + logf(512.0f);
    }
  }
}

// ---------------------------------------------------------------------------
extern "C" void kernel_launch(void* const* d_in, const int* in_sizes, int n_in,
                              void* d_out, int out_size, void* d_ws, size_t ws_size,
                              hipStream_t stream) {
  const float* x   = (const float*)d_in[0];
  const float* y   = (const float*)d_in[1];
  const float* W1x = (const float*)d_in[2];
  const float* W1y = (const float*)d_in[3];
  const float* b1  = (const float*)d_in[4];
  const float* W2  = (const float*)d_in[5];
  const float* b2  = (const float*)d_in[6];
  const float* W3  = (const float*)d_in[7];
  const float* b3  = (const float*)d_in[8];

  float* ws = (float*)d_ws;
  float* hx  = ws;                        // 512*512 f32
  float* hy  = ws + 262144;               // 512*512 f32
  float* t0g = ws + 524288;               // 512 f32 (diag = T0)
  float* rsm = ws + 524288 + 512;         // 512 f32 (row exp-sums)
  int*   ctl = (int*)(ws + 524288 + 1024);// rank counter
  __bf16* w2h = (__bf16*)(ws + 786432);   // 512*512 bf16 (fragment-major)
  float* out = (float*)d_out;

  static bool configured = false;
  if (!configured) {
    hipFuncSetAttribute(reinterpret_cast<const void*>(pair_kernel),
                        hipFuncAttributeMaxDynamicSharedMemorySize,
                        64 * SPA * 2);
    configured = true;
  }

  hipLaunchKernelGGL(prep_kernel, dim3(640), dim3(256), 0, stream,
                     x, y, W1x, W1y, b1, W2, hx, hy, w2h, rsm, ctl);
  hipLaunchKernelGGL(pair_kernel, dim3(NTILE), dim3(512), 64 * SPA * 2, stream,
                     hx, hy, w2h, b2, W3, b3, t0g, rsm, ctl, out);
}